// Round 1
// baseline (442.966 us; speedup 1.0000x reference)
//
#include <hip/hip_runtime.h>
#include <hip/hip_bf16.h>

#define N_NODES 50000
#define N_EDGES 800000
#define F 128
#define NC 41

__global__ void zero_deg_kernel(int* deg) {
    int i = blockIdx.x * blockDim.x + threadIdx.x;
    if (i < N_NODES) deg[i] = 0;
}

__global__ void count_deg_kernel(const int* __restrict__ dst, int* __restrict__ deg) {
    int e = blockIdx.x * blockDim.x + threadIdx.x;
    if (e < N_EDGES) atomicAdd(&deg[dst[e]], 1);
}

// Single-block exclusive scan over deg -> row_ptr (and cursor copy, inv_deg).
__global__ __launch_bounds__(1024) void scan_deg_kernel(const int* __restrict__ deg,
                                                        int* __restrict__ row_ptr,
                                                        int* __restrict__ cursor,
                                                        float* __restrict__ inv_deg) {
    __shared__ int buf[1024];
    __shared__ int carry;
    int tid = threadIdx.x;
    if (tid == 0) carry = 0;
    __syncthreads();
    for (int base = 0; base < N_NODES; base += 1024) {
        int i = base + tid;
        int v = (i < N_NODES) ? deg[i] : 0;
        buf[tid] = v;
        __syncthreads();
        for (int off = 1; off < 1024; off <<= 1) {
            int t = (tid >= off) ? buf[tid - off] : 0;
            __syncthreads();
            buf[tid] += t;
            __syncthreads();
        }
        int incl = buf[tid];
        int excl = incl - v;
        if (i < N_NODES) {
            int rp = carry + excl;
            row_ptr[i] = rp;
            cursor[i] = rp;
            inv_deg[i] = 1.0f / fmaxf((float)v, 1.0f);
        }
        __syncthreads();
        if (tid == 1023) carry += incl;
        __syncthreads();
    }
    if (tid == 0) row_ptr[N_NODES] = carry;
}

__global__ void fill_csr_kernel(const int* __restrict__ src, const int* __restrict__ dst,
                                int* __restrict__ cursor, int* __restrict__ csr_src) {
    int e = blockIdx.x * blockDim.x + threadIdx.x;
    if (e < N_EDGES) {
        int p = atomicAdd(&cursor[dst[e]], 1);
        csr_src[p] = src[e];
    }
}

// Wcat[128][128]: cols 0..40 = W_self1, cols 64..104 = W_neigh1, rest 0.
__global__ void build_wcat_kernel(const float* __restrict__ W1, const float* __restrict__ W2,
                                  float* __restrict__ Wcat) {
    int i = blockIdx.x * blockDim.x + threadIdx.x;
    if (i < F * F) {
        int k = i / F, c = i % F;
        float v = 0.0f;
        if (c < NC) v = W1[k * NC + c];
        else if (c >= 64 && c < 64 + NC) v = W2[k * NC + (c - 64)];
        Wcat[i] = v;
    }
}

// Per-node mean of x rows over in-edges (CSR). One wave per node; float2/lane.
__global__ __launch_bounds__(64) void agg_mean_kernel(const float* __restrict__ x,
                                                      const int* __restrict__ row_ptr,
                                                      const int* __restrict__ csr_src,
                                                      const float* __restrict__ inv_deg,
                                                      float* __restrict__ aggm) {
    int node = blockIdx.x;
    int t = threadIdx.x;
    int s = row_ptr[node], e = row_ptr[node + 1];
    float2 acc = make_float2(0.f, 0.f);
    for (int j = s; j < e; ++j) {
        int sr = csr_src[j];
        float2 v = ((const float2*)(x + (size_t)sr * F))[t];
        acc.x += v.x;
        acc.y += v.y;
    }
    float inv = inv_deg[node];
    ((float2*)(aggm + (size_t)node * F))[t] = make_float2(acc.x * inv, acc.y * inv);
}

// C[M][128] = A1@W1 (+ A2@W2) (+bias) (relu). 64x64 tile, 4x4 per thread.
__global__ __launch_bounds__(256) void gemm_fused_kernel(const float* __restrict__ A1,
                                                         const float* __restrict__ W1,
                                                         const float* __restrict__ A2,
                                                         const float* __restrict__ W2,
                                                         const float* __restrict__ bias,
                                                         float* __restrict__ out,
                                                         int M, int do_relu) {
    __shared__ float As[16][68];  // transposed A tile, padded stride 68 (16B-aligned rows, 2-way max conflict)
    __shared__ float Bs[16][64];
    int row0 = blockIdx.x * 64, col0 = blockIdx.y * 64;
    int tid = threadIdx.x;
    int tr = tid / 16, tc = tid % 16;
    float acc[4][4] = {};
    int nhalf = (A2 != nullptr) ? 2 : 1;
    for (int half = 0; half < nhalf; ++half) {
        const float* A = half ? A2 : A1;
        const float* W = half ? W2 : W1;
        for (int k0 = 0; k0 < F; k0 += 16) {
            int lr = tid >> 2;          // 0..63 (row in tile)
            int lk = (tid & 3) * 4;     // k quad
            int grow = row0 + lr;
            if (grow >= M) grow = M - 1;
            float4 av = *(const float4*)(A + (size_t)grow * F + k0 + lk);
            int bk = tid >> 4;          // 0..15
            int bc = (tid & 15) * 4;
            float4 bv = *(const float4*)(W + (size_t)(k0 + bk) * F + col0 + bc);
            __syncthreads();
            As[lk + 0][lr] = av.x;
            As[lk + 1][lr] = av.y;
            As[lk + 2][lr] = av.z;
            As[lk + 3][lr] = av.w;
            *(float4*)&Bs[bk][bc] = bv;
            __syncthreads();
#pragma unroll
            for (int kk = 0; kk < 16; ++kk) {
                float4 a = *(const float4*)&As[kk][tr * 4];
                float4 b = *(const float4*)&Bs[kk][tc * 4];
                float ar[4] = {a.x, a.y, a.z, a.w};
                float br[4] = {b.x, b.y, b.z, b.w};
#pragma unroll
                for (int i = 0; i < 4; ++i)
#pragma unroll
                    for (int j = 0; j < 4; ++j) acc[i][j] += ar[i] * br[j];
            }
        }
    }
#pragma unroll
    for (int i = 0; i < 4; ++i) {
        int r = row0 + tr * 4 + i;
        if (r < M) {
#pragma unroll
            for (int j = 0; j < 4; ++j) {
                int c = col0 + tc * 4 + j;
                float v = acc[i][j];
                if (bias) v += bias[c];
                if (do_relu) v = fmaxf(v, 0.0f);
                out[(size_t)r * F + c] = v;
            }
        }
    }
}

// out[node][c] = t[node][c] + b1[c] + inv_deg * sum_j t[src_j][64+c]
__global__ __launch_bounds__(64) void final_out_kernel(const float* __restrict__ t,
                                                       const int* __restrict__ row_ptr,
                                                       const int* __restrict__ csr_src,
                                                       const float* __restrict__ inv_deg,
                                                       const float* __restrict__ b1,
                                                       float* __restrict__ out) {
    int node = blockIdx.x;
    int c = threadIdx.x;
    if (c >= NC) return;
    int s = row_ptr[node], e = row_ptr[node + 1];
    float acc = 0.0f;
    for (int j = s; j < e; ++j) {
        int sr = csr_src[j];
        acc += t[(size_t)sr * F + 64 + c];
    }
    out[(size_t)node * NC + c] = t[(size_t)node * F + c] + b1[c] + acc * inv_deg[node];
}

extern "C" void kernel_launch(void* const* d_in, const int* in_sizes, int n_in,
                              void* d_out, int out_size, void* d_ws, size_t ws_size,
                              hipStream_t stream) {
    const float* x   = (const float*)d_in[0];
    const int*   src = (const int*)d_in[1];
    const int*   dst = (const int*)d_in[2];
    const float* Ws0 = (const float*)d_in[3];
    const float* Wn0 = (const float*)d_in[4];
    const float* b0  = (const float*)d_in[5];
    const float* Ws1 = (const float*)d_in[6];
    const float* Wn1 = (const float*)d_in[7];
    const float* b1  = (const float*)d_in[8];
    float* out = (float*)d_out;

    char* ws = (char*)d_ws;
    size_t o = 0;
    auto alloc = [&](size_t bytes) {
        size_t r = o;
        o = (o + bytes + 255) & ~(size_t)255;
        return r;
    };
    int*   deg     = (int*)(ws + alloc(sizeof(int) * N_NODES));
    int*   row_ptr = (int*)(ws + alloc(sizeof(int) * (N_NODES + 1)));
    int*   cursor  = (int*)(ws + alloc(sizeof(int) * N_NODES));
    int*   csr     = (int*)(ws + alloc(sizeof(int) * N_EDGES));
    float* inv_deg = (float*)(ws + alloc(sizeof(float) * N_NODES));
    float* Wcat    = (float*)(ws + alloc(sizeof(float) * F * F));
    float* aggm    = (float*)(ws + alloc(sizeof(float) * (size_t)N_NODES * F));  // reused as out_tmp
    float* h       = (float*)(ws + alloc(sizeof(float) * (size_t)N_NODES * F));

    zero_deg_kernel<<<(N_NODES + 255) / 256, 256, 0, stream>>>(deg);
    count_deg_kernel<<<(N_EDGES + 255) / 256, 256, 0, stream>>>(dst, deg);
    scan_deg_kernel<<<1, 1024, 0, stream>>>(deg, row_ptr, cursor, inv_deg);
    fill_csr_kernel<<<(N_EDGES + 255) / 256, 256, 0, stream>>>(src, dst, cursor, csr);
    build_wcat_kernel<<<(F * F + 255) / 256, 256, 0, stream>>>(Ws1, Wn1, Wcat);
    agg_mean_kernel<<<N_NODES, 64, 0, stream>>>(x, row_ptr, csr, inv_deg, aggm);
    // layer 0: h = relu(x@Ws0 + aggm@Wn0 + b0)
    gemm_fused_kernel<<<dim3((N_NODES + 63) / 64, 2), 256, 0, stream>>>(
        x, Ws0, aggm, Wn0, b0, h, N_NODES, 1);
    // layer 1 pre: t = h @ Wcat  (cols 0..40 self, 64..104 neigh)  -> reuse aggm
    gemm_fused_kernel<<<dim3((N_NODES + 63) / 64, 2), 256, 0, stream>>>(
        h, Wcat, nullptr, nullptr, nullptr, aggm, N_NODES, 0);
    final_out_kernel<<<N_NODES, 64, 0, stream>>>(aggm, row_ptr, csr, inv_deg, b1, out);
}

// Round 2
// 354.392 us; speedup vs baseline: 1.2499x; 1.2499x over previous
//
#include <hip/hip_runtime.h>
#include <hip/hip_bf16.h>

#define N_NODES 50000
#define N_EDGES 800000
#define F 128
#define NC 41
#define SCAN_BLK 256
#define N_SCAN_BLKS ((N_NODES + SCAN_BLK - 1) / SCAN_BLK)   // 196

__global__ void zero_deg_kernel(int* deg) {
    int i = blockIdx.x * blockDim.x + threadIdx.x;
    if (i < N_NODES) deg[i] = 0;
}

__global__ void count_deg_kernel(const int* __restrict__ dst, int* __restrict__ deg) {
    int e = blockIdx.x * blockDim.x + threadIdx.x;
    if (e < N_EDGES) atomicAdd(&deg[dst[e]], 1);
}

// Stage 1: per-block exclusive scan of deg (256/block) -> local, block sums -> bsum.
__global__ __launch_bounds__(SCAN_BLK) void scan1_kernel(const int* __restrict__ deg,
                                                         int* __restrict__ local,
                                                         int* __restrict__ bsum) {
    __shared__ int buf[SCAN_BLK];
    int tid = threadIdx.x;
    int i = blockIdx.x * SCAN_BLK + tid;
    int v = (i < N_NODES) ? deg[i] : 0;
    buf[tid] = v;
    __syncthreads();
#pragma unroll
    for (int off = 1; off < SCAN_BLK; off <<= 1) {
        int t = (tid >= off) ? buf[tid - off] : 0;
        __syncthreads();
        buf[tid] += t;
        __syncthreads();
    }
    if (i < N_NODES) local[i] = buf[tid] - v;
    if (tid == SCAN_BLK - 1) bsum[blockIdx.x] = buf[tid];
}

// Stage 2: single-block exclusive scan of the 196 block sums (in place); total -> row_ptr[N].
__global__ __launch_bounds__(SCAN_BLK) void scan2_kernel(int* __restrict__ bsum,
                                                         int* __restrict__ row_ptr) {
    __shared__ int buf[SCAN_BLK];
    int tid = threadIdx.x;
    int v = (tid < N_SCAN_BLKS) ? bsum[tid] : 0;
    buf[tid] = v;
    __syncthreads();
#pragma unroll
    for (int off = 1; off < SCAN_BLK; off <<= 1) {
        int t = (tid >= off) ? buf[tid - off] : 0;
        __syncthreads();
        buf[tid] += t;
        __syncthreads();
    }
    if (tid < N_SCAN_BLKS) bsum[tid] = buf[tid] - v;
    if (tid == SCAN_BLK - 1) row_ptr[N_NODES] = buf[tid];
}

// Stage 3: row_ptr = local + block offset; cursor copy; inv_deg.
__global__ __launch_bounds__(SCAN_BLK) void scan3_kernel(const int* __restrict__ deg,
                                                         const int* __restrict__ local,
                                                         const int* __restrict__ bsum,
                                                         int* __restrict__ row_ptr,
                                                         int* __restrict__ cursor,
                                                         float* __restrict__ inv_deg) {
    int i = blockIdx.x * SCAN_BLK + threadIdx.x;
    if (i < N_NODES) {
        int rp = local[i] + bsum[blockIdx.x];
        row_ptr[i] = rp;
        cursor[i] = rp;
        inv_deg[i] = 1.0f / fmaxf((float)deg[i], 1.0f);
    }
}

__global__ void fill_csr_kernel(const int* __restrict__ src, const int* __restrict__ dst,
                                int* __restrict__ cursor, int* __restrict__ csr_src) {
    int e = blockIdx.x * blockDim.x + threadIdx.x;
    if (e < N_EDGES) {
        int p = atomicAdd(&cursor[dst[e]], 1);
        csr_src[p] = src[e];
    }
}

// Wcat[128][128]: cols 0..40 = W_self1, cols 64..104 = W_neigh1, rest 0.
__global__ void build_wcat_kernel(const float* __restrict__ W1, const float* __restrict__ W2,
                                  float* __restrict__ Wcat) {
    int i = blockIdx.x * blockDim.x + threadIdx.x;
    if (i < F * F) {
        int k = i / F, c = i % F;
        float v = 0.0f;
        if (c < NC) v = W1[k * NC + c];
        else if (c >= 64 && c < 64 + NC) v = W2[k * NC + (c - 64)];
        Wcat[i] = v;
    }
}

// Per-node mean of x rows over in-edges (CSR). One wave per node; float2/lane.
__global__ __launch_bounds__(64) void agg_mean_kernel(const float* __restrict__ x,
                                                      const int* __restrict__ row_ptr,
                                                      const int* __restrict__ csr_src,
                                                      const float* __restrict__ inv_deg,
                                                      float* __restrict__ aggm) {
    int node = blockIdx.x;
    int t = threadIdx.x;
    int s = row_ptr[node], e = row_ptr[node + 1];
    float2 acc = make_float2(0.f, 0.f);
    for (int j = s; j < e; ++j) {
        int sr = csr_src[j];
        float2 v = ((const float2*)(x + (size_t)sr * F))[t];
        acc.x += v.x;
        acc.y += v.y;
    }
    float inv = inv_deg[node];
    ((float2*)(aggm + (size_t)node * F))[t] = make_float2(acc.x * inv, acc.y * inv);
}

// C[M][128] = A1@W1 (+ A2@W2) (+bias) (relu). 64x64 tile, 4x4 per thread.
__global__ __launch_bounds__(256) void gemm_fused_kernel(const float* __restrict__ A1,
                                                         const float* __restrict__ W1,
                                                         const float* __restrict__ A2,
                                                         const float* __restrict__ W2,
                                                         const float* __restrict__ bias,
                                                         float* __restrict__ out,
                                                         int M, int do_relu) {
    __shared__ float As[16][68];  // transposed A tile, padded stride
    __shared__ float Bs[16][64];
    int row0 = blockIdx.x * 64, col0 = blockIdx.y * 64;
    int tid = threadIdx.x;
    int tr = tid / 16, tc = tid % 16;
    float acc[4][4] = {};
    int nhalf = (A2 != nullptr) ? 2 : 1;
    for (int half = 0; half < nhalf; ++half) {
        const float* A = half ? A2 : A1;
        const float* W = half ? W2 : W1;
        for (int k0 = 0; k0 < F; k0 += 16) {
            int lr = tid >> 2;          // 0..63 (row in tile)
            int lk = (tid & 3) * 4;     // k quad
            int grow = row0 + lr;
            if (grow >= M) grow = M - 1;
            float4 av = *(const float4*)(A + (size_t)grow * F + k0 + lk);
            int bk = tid >> 4;          // 0..15
            int bc = (tid & 15) * 4;
            float4 bv = *(const float4*)(W + (size_t)(k0 + bk) * F + col0 + bc);
            __syncthreads();
            As[lk + 0][lr] = av.x;
            As[lk + 1][lr] = av.y;
            As[lk + 2][lr] = av.z;
            As[lk + 3][lr] = av.w;
            *(float4*)&Bs[bk][bc] = bv;
            __syncthreads();
#pragma unroll
            for (int kk = 0; kk < 16; ++kk) {
                float4 a = *(const float4*)&As[kk][tr * 4];
                float4 b = *(const float4*)&Bs[kk][tc * 4];
                float ar[4] = {a.x, a.y, a.z, a.w};
                float br[4] = {b.x, b.y, b.z, b.w};
#pragma unroll
                for (int i = 0; i < 4; ++i)
#pragma unroll
                    for (int j = 0; j < 4; ++j) acc[i][j] += ar[i] * br[j];
            }
        }
    }
#pragma unroll
    for (int i = 0; i < 4; ++i) {
        int r = row0 + tr * 4 + i;
        if (r < M) {
#pragma unroll
            for (int j = 0; j < 4; ++j) {
                int c = col0 + tc * 4 + j;
                float v = acc[i][j];
                if (bias) v += bias[c];
                if (do_relu) v = fmaxf(v, 0.0f);
                out[(size_t)r * F + c] = v;
            }
        }
    }
}

// out[node][c] = t[node][c] + b1[c] + inv_deg * sum_j t[src_j][64+c]
__global__ __launch_bounds__(64) void final_out_kernel(const float* __restrict__ t,
                                                       const int* __restrict__ row_ptr,
                                                       const int* __restrict__ csr_src,
                                                       const float* __restrict__ inv_deg,
                                                       const float* __restrict__ b1,
                                                       float* __restrict__ out) {
    int node = blockIdx.x;
    int c = threadIdx.x;
    if (c >= NC) return;
    int s = row_ptr[node], e = row_ptr[node + 1];
    float acc = 0.0f;
    for (int j = s; j < e; ++j) {
        int sr = csr_src[j];
        acc += t[(size_t)sr * F + 64 + c];
    }
    out[(size_t)node * NC + c] = t[(size_t)node * F + c] + b1[c] + acc * inv_deg[node];
}

extern "C" void kernel_launch(void* const* d_in, const int* in_sizes, int n_in,
                              void* d_out, int out_size, void* d_ws, size_t ws_size,
                              hipStream_t stream) {
    const float* x   = (const float*)d_in[0];
    const int*   src = (const int*)d_in[1];
    const int*   dst = (const int*)d_in[2];
    const float* Ws0 = (const float*)d_in[3];
    const float* Wn0 = (const float*)d_in[4];
    const float* b0  = (const float*)d_in[5];
    const float* Ws1 = (const float*)d_in[6];
    const float* Wn1 = (const float*)d_in[7];
    const float* b1  = (const float*)d_in[8];
    float* out = (float*)d_out;

    char* ws = (char*)d_ws;
    size_t o = 0;
    auto alloc = [&](size_t bytes) {
        size_t r = o;
        o = (o + bytes + 255) & ~(size_t)255;
        return r;
    };
    int*   deg     = (int*)(ws + alloc(sizeof(int) * N_NODES));
    int*   local   = (int*)(ws + alloc(sizeof(int) * N_NODES));
    int*   bsum    = (int*)(ws + alloc(sizeof(int) * N_SCAN_BLKS));
    int*   row_ptr = (int*)(ws + alloc(sizeof(int) * (N_NODES + 1)));
    int*   cursor  = (int*)(ws + alloc(sizeof(int) * N_NODES));
    int*   csr     = (int*)(ws + alloc(sizeof(int) * N_EDGES));
    float* inv_deg = (float*)(ws + alloc(sizeof(float) * N_NODES));
    float* Wcat    = (float*)(ws + alloc(sizeof(float) * F * F));
    float* aggm    = (float*)(ws + alloc(sizeof(float) * (size_t)N_NODES * F));  // reused as out_tmp
    float* h       = (float*)(ws + alloc(sizeof(float) * (size_t)N_NODES * F));

    zero_deg_kernel<<<(N_NODES + 255) / 256, 256, 0, stream>>>(deg);
    count_deg_kernel<<<(N_EDGES + 255) / 256, 256, 0, stream>>>(dst, deg);
    scan1_kernel<<<N_SCAN_BLKS, SCAN_BLK, 0, stream>>>(deg, local, bsum);
    scan2_kernel<<<1, SCAN_BLK, 0, stream>>>(bsum, row_ptr);
    scan3_kernel<<<N_SCAN_BLKS, SCAN_BLK, 0, stream>>>(deg, local, bsum, row_ptr, cursor, inv_deg);
    fill_csr_kernel<<<(N_EDGES + 255) / 256, 256, 0, stream>>>(src, dst, cursor, csr);
    build_wcat_kernel<<<(F * F + 255) / 256, 256, 0, stream>>>(Ws1, Wn1, Wcat);
    agg_mean_kernel<<<N_NODES, 64, 0, stream>>>(x, row_ptr, csr, inv_deg, aggm);
    // layer 0: h = relu(x@Ws0 + aggm@Wn0 + b0)
    gemm_fused_kernel<<<dim3((N_NODES + 63) / 64, 2), 256, 0, stream>>>(
        x, Ws0, aggm, Wn0, b0, h, N_NODES, 1);
    // layer 1 pre: t = h @ Wcat  (cols 0..40 self, 64..104 neigh)  -> reuse aggm
    gemm_fused_kernel<<<dim3((N_NODES + 63) / 64, 2), 256, 0, stream>>>(
        h, Wcat, nullptr, nullptr, nullptr, aggm, N_NODES, 0);
    final_out_kernel<<<N_NODES, 64, 0, stream>>>(aggm, row_ptr, csr, inv_deg, b1, out);
}

// Round 3
// 346.611 us; speedup vs baseline: 1.2780x; 1.0224x over previous
//
#include <hip/hip_runtime.h>
#include <hip/hip_bf16.h>

#define N_NODES 50000
#define N_EDGES 800000
#define F 128
#define NC 41
#define SCAN_BLK 256
#define N_SCAN_BLKS ((N_NODES + SCAN_BLK - 1) / SCAN_BLK)   // 196

__device__ __forceinline__ float bf2f(unsigned short u) {
    unsigned int x = ((unsigned int)u) << 16;
    return __uint_as_float(x);
}
__device__ __forceinline__ unsigned short f2bf(float f) {
    // round-to-nearest-even bf16
    unsigned int x = __float_as_uint(f);
    unsigned int lsb = (x >> 16) & 1u;
    x += 0x7fffu + lsb;
    return (unsigned short)(x >> 16);
}

__global__ void zero_deg_kernel(int* deg) {
    int i = blockIdx.x * blockDim.x + threadIdx.x;
    if (i < N_NODES) deg[i] = 0;
}

__global__ void count_deg_kernel(const int* __restrict__ dst, int* __restrict__ deg) {
    int e = blockIdx.x * blockDim.x + threadIdx.x;
    if (e < N_EDGES) atomicAdd(&deg[dst[e]], 1);
}

__global__ __launch_bounds__(SCAN_BLK) void scan1_kernel(const int* __restrict__ deg,
                                                         int* __restrict__ local,
                                                         int* __restrict__ bsum) {
    __shared__ int buf[SCAN_BLK];
    int tid = threadIdx.x;
    int i = blockIdx.x * SCAN_BLK + tid;
    int v = (i < N_NODES) ? deg[i] : 0;
    buf[tid] = v;
    __syncthreads();
#pragma unroll
    for (int off = 1; off < SCAN_BLK; off <<= 1) {
        int t = (tid >= off) ? buf[tid - off] : 0;
        __syncthreads();
        buf[tid] += t;
        __syncthreads();
    }
    if (i < N_NODES) local[i] = buf[tid] - v;
    if (tid == SCAN_BLK - 1) bsum[blockIdx.x] = buf[tid];
}

__global__ __launch_bounds__(SCAN_BLK) void scan2_kernel(int* __restrict__ bsum,
                                                         int* __restrict__ row_ptr) {
    __shared__ int buf[SCAN_BLK];
    int tid = threadIdx.x;
    int v = (tid < N_SCAN_BLKS) ? bsum[tid] : 0;
    buf[tid] = v;
    __syncthreads();
#pragma unroll
    for (int off = 1; off < SCAN_BLK; off <<= 1) {
        int t = (tid >= off) ? buf[tid - off] : 0;
        __syncthreads();
        buf[tid] += t;
        __syncthreads();
    }
    if (tid < N_SCAN_BLKS) bsum[tid] = buf[tid] - v;
    if (tid == SCAN_BLK - 1) row_ptr[N_NODES] = buf[tid];
}

__global__ __launch_bounds__(SCAN_BLK) void scan3_kernel(const int* __restrict__ deg,
                                                         const int* __restrict__ local,
                                                         const int* __restrict__ bsum,
                                                         int* __restrict__ row_ptr,
                                                         int* __restrict__ cursor,
                                                         float* __restrict__ inv_deg) {
    int i = blockIdx.x * SCAN_BLK + threadIdx.x;
    if (i < N_NODES) {
        int rp = local[i] + bsum[blockIdx.x];
        row_ptr[i] = rp;
        cursor[i] = rp;
        inv_deg[i] = 1.0f / fmaxf((float)deg[i], 1.0f);
    }
}

__global__ void fill_csr_kernel(const int* __restrict__ src, const int* __restrict__ dst,
                                int* __restrict__ cursor, int* __restrict__ csr_src) {
    int e = blockIdx.x * blockDim.x + threadIdx.x;
    if (e < N_EDGES) {
        int p = atomicAdd(&cursor[dst[e]], 1);
        csr_src[p] = src[e];
    }
}

// Wcat0 [128][256]: cols 0..127 = W_self0, 128..255 = W_neigh0.
__global__ void build_wcat0_kernel(const float* __restrict__ Ws, const float* __restrict__ Wn,
                                   float* __restrict__ Wcat) {
    int i = blockIdx.x * blockDim.x + threadIdx.x;
    if (i < F * 2 * F) {
        int k = i / (2 * F), c = i % (2 * F);
        Wcat[i] = (c < F) ? Ws[k * F + c] : Wn[k * F + (c - F)];
    }
}

// Wcat1 [128][128]: cols 0..40 = W_self1, 64..104 = W_neigh1, rest 0.
__global__ void build_wcat1_kernel(const float* __restrict__ W1, const float* __restrict__ W2,
                                   float* __restrict__ Wcat) {
    int i = blockIdx.x * blockDim.x + threadIdx.x;
    if (i < F * F) {
        int k = i / F, c = i % F;
        float v = 0.0f;
        if (c < NC) v = W1[k * NC + c];
        else if (c >= 64 && c < 64 + NC) v = W2[k * NC + (c - 64)];
        Wcat[i] = v;
    }
}

// C[M][Ntot] = A[M][128] @ W[128][Ntot]. 64x64 tile per block, 4x4 per thread.
// cols < split -> outF (fp32, ld ldF, only col<ldF written)
// cols >= split -> outH (bf16, ld ldH, only (col-split)<ldH written)
__global__ __launch_bounds__(256) void gemm_dual_kernel(const float* __restrict__ A,
                                                        const float* __restrict__ W, int ldw,
                                                        int M, int split,
                                                        float* __restrict__ outF, int ldF,
                                                        unsigned short* __restrict__ outH, int ldH) {
    __shared__ float As[16][68];  // transposed A tile, padded stride
    __shared__ float Bs[16][64];
    int row0 = blockIdx.x * 64, col0 = blockIdx.y * 64;
    int tid = threadIdx.x;
    int tr = tid / 16, tc = tid % 16;
    float acc[4][4] = {};
    for (int k0 = 0; k0 < F; k0 += 16) {
        int lr = tid >> 2;          // 0..63 (row in tile)
        int lk = (tid & 3) * 4;     // k quad
        int grow = row0 + lr;
        if (grow >= M) grow = M - 1;
        float4 av = *(const float4*)(A + (size_t)grow * F + k0 + lk);
        int bk = tid >> 4;          // 0..15
        int bc = (tid & 15) * 4;
        float4 bv = *(const float4*)(W + (size_t)(k0 + bk) * ldw + col0 + bc);
        __syncthreads();
        As[lk + 0][lr] = av.x;
        As[lk + 1][lr] = av.y;
        As[lk + 2][lr] = av.z;
        As[lk + 3][lr] = av.w;
        *(float4*)&Bs[bk][bc] = bv;
        __syncthreads();
#pragma unroll
        for (int kk = 0; kk < 16; ++kk) {
            float4 a = *(const float4*)&As[kk][tr * 4];
            float4 b = *(const float4*)&Bs[kk][tc * 4];
            float ar[4] = {a.x, a.y, a.z, a.w};
            float br[4] = {b.x, b.y, b.z, b.w};
#pragma unroll
            for (int i = 0; i < 4; ++i)
#pragma unroll
                for (int j = 0; j < 4; ++j) acc[i][j] += ar[i] * br[j];
        }
    }
#pragma unroll
    for (int i = 0; i < 4; ++i) {
        int r = row0 + tr * 4 + i;
        if (r < M) {
#pragma unroll
            for (int j = 0; j < 4; ++j) {
                int c = col0 + tc * 4 + j;
                float v = acc[i][j];
                if (c < split) {
                    if (c < ldF) outF[(size_t)r * ldF + c] = v;
                } else {
                    int cb = c - split;
                    if (cb < ldH) outH[(size_t)r * ldH + cb] = f2bf(v);
                }
            }
        }
    }
}

// h[node] = relu(u_self[node] + inv_deg * sum_j u_neigh[src_j] + b0). One wave/node.
__global__ __launch_bounds__(64) void agg0_kernel(const float* __restrict__ u_self,
                                                  const unsigned short* __restrict__ u_neigh,
                                                  const int* __restrict__ row_ptr,
                                                  const int* __restrict__ csr_src,
                                                  const float* __restrict__ inv_deg,
                                                  const float* __restrict__ b0,
                                                  float* __restrict__ h) {
    int node = blockIdx.x;
    int t = threadIdx.x;
    int s = row_ptr[node], e = row_ptr[node + 1];
    const unsigned int* un = (const unsigned int*)u_neigh;  // 2 bf16 per uint
    float ax = 0.f, ay = 0.f;
    for (int j = s; j < e; ++j) {
        int sr = csr_src[j];
        unsigned int v = un[(size_t)sr * (F / 2) + t];
        ax += bf2f((unsigned short)(v & 0xffffu));
        ay += bf2f((unsigned short)(v >> 16));
    }
    float inv = inv_deg[node];
    float2 us = ((const float2*)(u_self + (size_t)node * F))[t];
    float2 bb = ((const float2*)b0)[t];
    float h0 = fmaxf(us.x + ax * inv + bb.x, 0.0f);
    float h1 = fmaxf(us.y + ay * inv + bb.y, 0.0f);
    ((float2*)(h + (size_t)node * F))[t] = make_float2(h0, h1);
}

// out[node][c] = t_self[node][c] + b1[c] + inv_deg * mean-sum of t_neigh[src][c]
// t_neigh is bf16 [N][48]; lanes 0..23 each handle 2 cols via uint loads.
__global__ __launch_bounds__(64) void final_out_kernel(const float* __restrict__ t_self,
                                                       const unsigned short* __restrict__ t_neigh,
                                                       const int* __restrict__ row_ptr,
                                                       const int* __restrict__ csr_src,
                                                       const float* __restrict__ inv_deg,
                                                       const float* __restrict__ b1,
                                                       float* __restrict__ out) {
    int node = blockIdx.x;
    int c = threadIdx.x;  // 0..63, active 0..23
    if (c >= 24) return;
    int s = row_ptr[node], e = row_ptr[node + 1];
    const unsigned int* tn = (const unsigned int*)t_neigh;  // 24 uints per row
    float ax = 0.f, ay = 0.f;
    for (int j = s; j < e; ++j) {
        int sr = csr_src[j];
        unsigned int v = tn[(size_t)sr * 24 + c];
        ax += bf2f((unsigned short)(v & 0xffffu));
        ay += bf2f((unsigned short)(v >> 16));
    }
    float inv = inv_deg[node];
    int c0 = 2 * c, c1 = 2 * c + 1;
    if (c0 < NC)
        out[(size_t)node * NC + c0] = t_self[(size_t)node * 48 + c0] + b1[c0] + ax * inv;
    if (c1 < NC)
        out[(size_t)node * NC + c1] = t_self[(size_t)node * 48 + c1] + b1[c1] + ay * inv;
}

extern "C" void kernel_launch(void* const* d_in, const int* in_sizes, int n_in,
                              void* d_out, int out_size, void* d_ws, size_t ws_size,
                              hipStream_t stream) {
    const float* x   = (const float*)d_in[0];
    const int*   src = (const int*)d_in[1];
    const int*   dst = (const int*)d_in[2];
    const float* Ws0 = (const float*)d_in[3];
    const float* Wn0 = (const float*)d_in[4];
    const float* b0  = (const float*)d_in[5];
    const float* Ws1 = (const float*)d_in[6];
    const float* Wn1 = (const float*)d_in[7];
    const float* b1  = (const float*)d_in[8];
    float* out = (float*)d_out;

    char* ws = (char*)d_ws;
    size_t o = 0;
    auto alloc = [&](size_t bytes) {
        size_t r = o;
        o = (o + bytes + 255) & ~(size_t)255;
        return r;
    };
    int*   deg     = (int*)(ws + alloc(sizeof(int) * N_NODES));
    int*   local   = (int*)(ws + alloc(sizeof(int) * N_NODES));
    int*   bsum    = (int*)(ws + alloc(sizeof(int) * N_SCAN_BLKS));
    int*   row_ptr = (int*)(ws + alloc(sizeof(int) * (N_NODES + 1)));
    int*   cursor  = (int*)(ws + alloc(sizeof(int) * N_NODES));
    int*   csr     = (int*)(ws + alloc(sizeof(int) * N_EDGES));
    float* inv_deg = (float*)(ws + alloc(sizeof(float) * N_NODES));
    float* Wcat0   = (float*)(ws + alloc(sizeof(float) * F * 2 * F));
    float* Wcat1   = (float*)(ws + alloc(sizeof(float) * F * F));
    float* u_self  = (float*)(ws + alloc(sizeof(float) * (size_t)N_NODES * F));
    unsigned short* u_neigh = (unsigned short*)(ws + alloc(sizeof(short) * (size_t)N_NODES * F));
    float* h       = (float*)(ws + alloc(sizeof(float) * (size_t)N_NODES * F));
    // t_self / t_neigh alias u_self / u_neigh (dead after agg0)
    float* t_self  = u_self;               // [N][48] fp32
    unsigned short* t_neigh = u_neigh;     // [N][48] bf16

    zero_deg_kernel<<<(N_NODES + 255) / 256, 256, 0, stream>>>(deg);
    count_deg_kernel<<<(N_EDGES + 255) / 256, 256, 0, stream>>>(dst, deg);
    scan1_kernel<<<N_SCAN_BLKS, SCAN_BLK, 0, stream>>>(deg, local, bsum);
    scan2_kernel<<<1, SCAN_BLK, 0, stream>>>(bsum, row_ptr);
    scan3_kernel<<<N_SCAN_BLKS, SCAN_BLK, 0, stream>>>(deg, local, bsum, row_ptr, cursor, inv_deg);
    fill_csr_kernel<<<(N_EDGES + 255) / 256, 256, 0, stream>>>(src, dst, cursor, csr);
    build_wcat0_kernel<<<(F * 2 * F + 255) / 256, 256, 0, stream>>>(Ws0, Wn0, Wcat0);
    build_wcat1_kernel<<<(F * F + 255) / 256, 256, 0, stream>>>(Ws1, Wn1, Wcat1);

    // GEMM A: u = x @ Wcat0 ; cols<128 -> u_self fp32, cols>=128 -> u_neigh bf16
    gemm_dual_kernel<<<dim3((N_NODES + 63) / 64, 4), 256, 0, stream>>>(
        x, Wcat0, 2 * F, N_NODES, F, u_self, F, u_neigh, F);
    // agg0: h = relu(u_self + mean(u_neigh) + b0)
    agg0_kernel<<<N_NODES, 64, 0, stream>>>(u_self, u_neigh, row_ptr, csr, inv_deg, b0, h);
    // GEMM B: t = h @ Wcat1 ; cols<64 (0..47) -> t_self fp32[48], cols 64..111 -> t_neigh bf16[48]
    gemm_dual_kernel<<<dim3((N_NODES + 63) / 64, 2), 256, 0, stream>>>(
        h, Wcat1, F, N_NODES, 64, t_self, 48, t_neigh, 48);
    // final: out = t_self + b1 + mean(t_neigh)
    final_out_kernel<<<N_NODES, 64, 0, stream>>>(t_self, t_neigh, row_ptr, csr, inv_deg, b1, out);
}

// Round 6
// 302.506 us; speedup vs baseline: 1.4643x; 1.1458x over previous
//
#include <hip/hip_runtime.h>
#include <hip/hip_bf16.h>

#define N_NODES 50000
#define N_EDGES 800000
#define F 128
#define NC 41
#define SCAN_BLK 256
#define N_SCAN_BLKS ((N_NODES + SCAN_BLK - 1) / SCAN_BLK)   // 196

typedef __attribute__((ext_vector_type(4))) float f32x4;
typedef __attribute__((ext_vector_type(8))) short bf16x8;   // 8 bf16 = 4 VGPRs

__device__ __forceinline__ float bf2f(unsigned short u) {
    unsigned int x = ((unsigned int)u) << 16;
    return __uint_as_float(x);
}
__device__ __forceinline__ unsigned short f2bf(float f) {
    unsigned int x = __float_as_uint(f);
    unsigned int lsb = (x >> 16) & 1u;
    x += 0x7fffu + lsb;
    return (unsigned short)(x >> 16);
}

__global__ void zero_deg_kernel(int* deg) {
    int i = blockIdx.x * blockDim.x + threadIdx.x;
    if (i < N_NODES) deg[i] = 0;
}

__global__ void count_deg_kernel(const int* __restrict__ dst, int* __restrict__ deg) {
    int e = blockIdx.x * blockDim.x + threadIdx.x;
    if (e < N_EDGES) atomicAdd(&deg[dst[e]], 1);
}

__global__ __launch_bounds__(SCAN_BLK) void scan1_kernel(const int* __restrict__ deg,
                                                         int* __restrict__ local,
                                                         int* __restrict__ bsum) {
    __shared__ int buf[SCAN_BLK];
    int tid = threadIdx.x;
    int i = blockIdx.x * SCAN_BLK + tid;
    int v = (i < N_NODES) ? deg[i] : 0;
    buf[tid] = v;
    __syncthreads();
#pragma unroll
    for (int off = 1; off < SCAN_BLK; off <<= 1) {
        int t = (tid >= off) ? buf[tid - off] : 0;
        __syncthreads();
        buf[tid] += t;
        __syncthreads();
    }
    if (i < N_NODES) local[i] = buf[tid] - v;
    if (tid == SCAN_BLK - 1) bsum[blockIdx.x] = buf[tid];
}

__global__ __launch_bounds__(SCAN_BLK) void scan2_kernel(int* __restrict__ bsum,
                                                         int* __restrict__ row_ptr) {
    __shared__ int buf[SCAN_BLK];
    int tid = threadIdx.x;
    int v = (tid < N_SCAN_BLKS) ? bsum[tid] : 0;
    buf[tid] = v;
    __syncthreads();
#pragma unroll
    for (int off = 1; off < SCAN_BLK; off <<= 1) {
        int t = (tid >= off) ? buf[tid - off] : 0;
        __syncthreads();
        buf[tid] += t;
        __syncthreads();
    }
    if (tid < N_SCAN_BLKS) bsum[tid] = buf[tid] - v;
    if (tid == SCAN_BLK - 1) row_ptr[N_NODES] = buf[tid];
}

__global__ __launch_bounds__(SCAN_BLK) void scan3_kernel(const int* __restrict__ deg,
                                                         const int* __restrict__ local,
                                                         const int* __restrict__ bsum,
                                                         int* __restrict__ row_ptr,
                                                         int* __restrict__ cursor,
                                                         float* __restrict__ inv_deg) {
    int i = blockIdx.x * SCAN_BLK + threadIdx.x;
    if (i < N_NODES) {
        int rp = local[i] + bsum[blockIdx.x];
        row_ptr[i] = rp;
        cursor[i] = rp;
        inv_deg[i] = 1.0f / fmaxf((float)deg[i], 1.0f);
    }
}

__global__ void fill_csr_kernel(const int* __restrict__ src, const int* __restrict__ dst,
                                int* __restrict__ cursor, int* __restrict__ csr_src) {
    int e = blockIdx.x * blockDim.x + threadIdx.x;
    if (e < N_EDGES) {
        int p = atomicAdd(&cursor[dst[e]], 1);
        csr_src[p] = src[e];
    }
}

// Pack GEMM-A weights into MFMA B-fragment order (bf16).
// Bpk[((ct*4+kb)*64+l)*8+j] = W[k][c], k=kb*32+(l>>4)*8+j, c=ct*16+(l&15).
// Logical W[128][256] = [W_self0 | W_neigh0].
__global__ void pack_w0_kernel(const float* __restrict__ Ws, const float* __restrict__ Wn,
                               unsigned short* __restrict__ Bpk) {
    int i = blockIdx.x * blockDim.x + threadIdx.x;
    if (i >= 128 * 256) return;
    int j = i & 7, l = (i >> 3) & 63, kb = (i >> 9) & 3, ct = i >> 11;
    int k = kb * 32 + (l >> 4) * 8 + j;
    int c = ct * 16 + (l & 15);
    float v = (c < F) ? Ws[k * F + c] : Wn[k * F + (c - F)];
    Bpk[i] = f2bf(v);
}

// Pack GEMM-B weights: logical W[128][128], cols 0..40 = W_self1, 64..104 = W_neigh1, else 0.
__global__ void pack_w1_kernel(const float* __restrict__ Ws, const float* __restrict__ Wn,
                               unsigned short* __restrict__ Bpk) {
    int i = blockIdx.x * blockDim.x + threadIdx.x;
    if (i >= 128 * 128) return;
    int j = i & 7, l = (i >> 3) & 63, kb = (i >> 9) & 3, ct = i >> 11;
    int k = kb * 32 + (l >> 4) * 8 + j;
    int c = ct * 16 + (l & 15);
    float v = 0.0f;
    if (c < 48) { if (c < NC) v = Ws[k * NC + c]; }
    else if (c >= 64 && c < 112) { int cc = c - 64; if (cc < NC) v = Wn[k * NC + cc]; }
    Bpk[i] = f2bf(v);
}

// MFMA GEMM: C[M][4*CT*16] = A[M][128] @ W. 64-row tile/block, 4 waves, wave covers CT*16 cols.
// AF32: A is fp32 (converted to bf16 during LDS staging); else A is bf16.
// MODE 0: write all cols bf16 to outA[M][CT*64].
// MODE 1 (CT=2): cols<48 -> outA[M][48], 64<=c<112 -> outB[M][48] (both bf16).
template<bool AF32, int CT, int MODE>
__global__ __launch_bounds__(256) void gemm_mfma_kernel(const void* __restrict__ Av,
                                                        const unsigned short* __restrict__ Bpk,
                                                        int M,
                                                        unsigned short* __restrict__ outA,
                                                        unsigned short* __restrict__ outB) {
    __shared__ unsigned short As[64 * 128];  // bf16, XOR-swizzled: idx ^= (row&7)<<3
    int tid = threadIdx.x;
    int wave = tid >> 6, lane = tid & 63;
    int row0 = blockIdx.x * 64;

    if (AF32) {
        const float* A = (const float*)Av;
#pragma unroll
        for (int i = 0; i < 8; ++i) {
            int fid = tid + i * 256;            // float4 id: 2048 total (64 rows x 32)
            int row = fid >> 5, c4 = (fid & 31) * 4;
            int grow = row0 + row; if (grow > M - 1) grow = M - 1;
            f32x4 v = *(const f32x4*)(A + (size_t)grow * F + c4);
            unsigned int p0 = (unsigned)f2bf(v.x) | ((unsigned)f2bf(v.y) << 16);
            unsigned int p1 = (unsigned)f2bf(v.z) | ((unsigned)f2bf(v.w) << 16);
            int idx = (row * 128 + c4) ^ ((row & 7) << 3);
            *(uint2*)&As[idx] = make_uint2(p0, p1);
        }
    } else {
        const unsigned short* A = (const unsigned short*)Av;
#pragma unroll
        for (int i = 0; i < 4; ++i) {
            int fid = tid + i * 256;            // uint4 id: 1024 total (64 rows x 16 chunks of 8 bf16)
            int row = fid >> 4, c8 = (fid & 15) * 8;
            int grow = row0 + row; if (grow > M - 1) grow = M - 1;
            uint4 v = *(const uint4*)&A[(size_t)grow * F + c8];
            int idx = (row * 128 + c8) ^ ((row & 7) << 3);
            *(uint4*)&As[idx] = v;
        }
    }
    __syncthreads();

    f32x4 acc[4][CT];
#pragma unroll
    for (int m = 0; m < 4; ++m)
#pragma unroll
        for (int n = 0; n < CT; ++n) acc[m][n] = (f32x4){0.f, 0.f, 0.f, 0.f};

#pragma unroll
    for (int kb = 0; kb < 4; ++kb) {
        bf16x8 afr[4];
#pragma unroll
        for (int m = 0; m < 4; ++m) {
            int row = m * 16 + (lane & 15);
            int ke = kb * 32 + (lane >> 4) * 8;
            int idx = (row * 128 + ke) ^ ((row & 7) << 3);
            afr[m] = *(const bf16x8*)&As[idx];
        }
#pragma unroll
        for (int n = 0; n < CT; ++n) {
            int ct = wave * CT + n;
            bf16x8 bfr = *(const bf16x8*)&Bpk[((ct * 4 + kb) * 64 + lane) * 8];
#pragma unroll
            for (int m = 0; m < 4; ++m)
                acc[m][n] = __builtin_amdgcn_mfma_f32_16x16x32_bf16(afr[m], bfr, acc[m][n], 0, 0, 0);
        }
    }

#pragma unroll
    for (int m = 0; m < 4; ++m) {
#pragma unroll
        for (int i = 0; i < 4; ++i) {
            int r = row0 + m * 16 + (lane >> 4) * 4 + i;
            if (r < M) {
#pragma unroll
                for (int n = 0; n < CT; ++n) {
                    int c = (wave * CT + n) * 16 + (lane & 15);
                    unsigned short val = f2bf(acc[m][n][i]);
                    if (MODE == 0) {
                        outA[(size_t)r * (CT * 64) + c] = val;
                    } else {
                        if (c < 48) outA[(size_t)r * 48 + c] = val;
                        else if (c >= 64 && c < 112) outB[(size_t)r * 48 + (c - 64)] = val;
                    }
                }
            }
        }
    }
}

// h[node] = relu(u_self + mean(u_neigh) + b0); u is bf16 [N][256] (self cols 0..127, neigh 128..255).
// One wave/node; lane t handles 2 cols via uint. h written bf16 [N][128].
__global__ __launch_bounds__(64) void agg0_kernel(const unsigned int* __restrict__ u,
                                                  const int* __restrict__ row_ptr,
                                                  const int* __restrict__ csr_src,
                                                  const float* __restrict__ inv_deg,
                                                  const float* __restrict__ b0,
                                                  unsigned int* __restrict__ hu) {
    int node = blockIdx.x;
    int t = threadIdx.x;
    int s = row_ptr[node], e = row_ptr[node + 1];
    float ax = 0.f, ay = 0.f;
    for (int j = s; j < e; ++j) {
        int sr = csr_src[j];
        unsigned int v = u[(size_t)sr * 128 + 64 + t];
        ax += bf2f((unsigned short)(v & 0xffffu));
        ay += bf2f((unsigned short)(v >> 16));
    }
    float inv = inv_deg[node];
    unsigned int vs = u[(size_t)node * 128 + t];
    float2 bb = ((const float2*)b0)[t];
    float h0 = fmaxf(bf2f((unsigned short)(vs & 0xffffu)) + ax * inv + bb.x, 0.0f);
    float h1 = fmaxf(bf2f((unsigned short)(vs >> 16)) + ay * inv + bb.y, 0.0f);
    hu[(size_t)node * 64 + t] = (unsigned)f2bf(h0) | ((unsigned)f2bf(h1) << 16);
}

// out[node][c] = t_self[node][c] + b1[c] + mean(t_neigh[src][c]); t_* bf16 [N][48].
__global__ __launch_bounds__(64) void final_out_kernel(const unsigned int* __restrict__ ts,
                                                       const unsigned int* __restrict__ tn,
                                                       const int* __restrict__ row_ptr,
                                                       const int* __restrict__ csr_src,
                                                       const float* __restrict__ inv_deg,
                                                       const float* __restrict__ b1,
                                                       float* __restrict__ out) {
    int node = blockIdx.x;
    int c = threadIdx.x;  // active 0..23
    if (c >= 24) return;
    int s = row_ptr[node], e = row_ptr[node + 1];
    float ax = 0.f, ay = 0.f;
    for (int j = s; j < e; ++j) {
        int sr = csr_src[j];
        unsigned int v = tn[(size_t)sr * 24 + c];
        ax += bf2f((unsigned short)(v & 0xffffu));
        ay += bf2f((unsigned short)(v >> 16));
    }
    float inv = inv_deg[node];
    unsigned int vs = ts[(size_t)node * 24 + c];
    int c0 = 2 * c, c1 = 2 * c + 1;
    if (c0 < NC)
        out[(size_t)node * NC + c0] = bf2f((unsigned short)(vs & 0xffffu)) + b1[c0] + ax * inv;
    if (c1 < NC)
        out[(size_t)node * NC + c1] = bf2f((unsigned short)(vs >> 16)) + b1[c1] + ay * inv;
}

extern "C" void kernel_launch(void* const* d_in, const int* in_sizes, int n_in,
                              void* d_out, int out_size, void* d_ws, size_t ws_size,
                              hipStream_t stream) {
    const float* x   = (const float*)d_in[0];
    const int*   src = (const int*)d_in[1];
    const int*   dst = (const int*)d_in[2];
    const float* Ws0 = (const float*)d_in[3];
    const float* Wn0 = (const float*)d_in[4];
    const float* b0  = (const float*)d_in[5];
    const float* Ws1 = (const float*)d_in[6];
    const float* Wn1 = (const float*)d_in[7];
    const float* b1  = (const float*)d_in[8];
    float* out = (float*)d_out;

    char* ws = (char*)d_ws;
    size_t o = 0;
    auto alloc = [&](size_t bytes) {
        size_t r = o;
        o = (o + bytes + 255) & ~(size_t)255;
        return r;
    };
    int*   deg     = (int*)(ws + alloc(sizeof(int) * N_NODES));
    int*   local   = (int*)(ws + alloc(sizeof(int) * N_NODES));
    int*   bsum    = (int*)(ws + alloc(sizeof(int) * N_SCAN_BLKS));
    int*   row_ptr = (int*)(ws + alloc(sizeof(int) * (N_NODES + 1)));
    int*   cursor  = (int*)(ws + alloc(sizeof(int) * N_NODES));
    int*   csr     = (int*)(ws + alloc(sizeof(int) * N_EDGES));
    float* inv_deg = (float*)(ws + alloc(sizeof(float) * N_NODES));
    unsigned short* Bpk0 = (unsigned short*)(ws + alloc(sizeof(short) * 128 * 256));
    unsigned short* Bpk1 = (unsigned short*)(ws + alloc(sizeof(short) * 128 * 128));
    unsigned short* u    = (unsigned short*)(ws + alloc(sizeof(short) * (size_t)N_NODES * 256));
    unsigned short* h    = (unsigned short*)(ws + alloc(sizeof(short) * (size_t)N_NODES * 128));
    unsigned short* t_self  = (unsigned short*)(ws + alloc(sizeof(short) * (size_t)N_NODES * 48));
    unsigned short* t_neigh = (unsigned short*)(ws + alloc(sizeof(short) * (size_t)N_NODES * 48));

    zero_deg_kernel<<<(N_NODES + 255) / 256, 256, 0, stream>>>(deg);
    count_deg_kernel<<<(N_EDGES + 255) / 256, 256, 0, stream>>>(dst, deg);
    scan1_kernel<<<N_SCAN_BLKS, SCAN_BLK, 0, stream>>>(deg, local, bsum);
    scan2_kernel<<<1, SCAN_BLK, 0, stream>>>(bsum, row_ptr);
    scan3_kernel<<<N_SCAN_BLKS, SCAN_BLK, 0, stream>>>(deg, local, bsum, row_ptr, cursor, inv_deg);
    fill_csr_kernel<<<(N_EDGES + 255) / 256, 256, 0, stream>>>(src, dst, cursor, csr);
    pack_w0_kernel<<<(128 * 256 + 255) / 256, 256, 0, stream>>>(Ws0, Wn0, Bpk0);
    pack_w1_kernel<<<(128 * 128 + 255) / 256, 256, 0, stream>>>(Ws1, Wn1, Bpk1);

    int nblk = (N_NODES + 63) / 64;  // 782
    // GEMM A: u = bf16(x) @ [Ws0|Wn0]  -> u bf16 [N][256]
    gemm_mfma_kernel<true, 4, 0><<<nblk, 256, 0, stream>>>(x, Bpk0, N_NODES, u, nullptr);
    // agg0: h = relu(u_self + mean(u_neigh) + b0) -> bf16 [N][128]
    agg0_kernel<<<N_NODES, 64, 0, stream>>>((const unsigned int*)u, row_ptr, csr, inv_deg, b0,
                                            (unsigned int*)h);
    // GEMM B: t = h @ Wcat1 -> t_self bf16[N][48], t_neigh bf16[N][48]
    gemm_mfma_kernel<false, 2, 1><<<nblk, 256, 0, stream>>>(h, Bpk1, N_NODES, t_self, t_neigh);
    // final: out = t_self + b1 + mean(t_neigh)
    final_out_kernel<<<N_NODES, 64, 0, stream>>>((const unsigned int*)t_self,
                                                 (const unsigned int*)t_neigh,
                                                 row_ptr, csr, inv_deg, b1, out);
}

// Round 7
// 298.686 us; speedup vs baseline: 1.4830x; 1.0128x over previous
//
#include <hip/hip_runtime.h>
#include <hip/hip_bf16.h>

#define N_NODES 50000
#define N_EDGES 800000
#define F 128
#define NC 41
#define SCAN_BLK 256
#define N_SCAN_BLKS ((N_NODES + SCAN_BLK - 1) / SCAN_BLK)   // 196
#define NSLICE 8
#define SLICE_NODES (N_NODES / NSLICE)   // 6250 exactly
#define FILL_BLKS_PER_SLICE 64

typedef __attribute__((ext_vector_type(4))) float f32x4;
typedef __attribute__((ext_vector_type(8))) short bf16x8;   // 8 bf16 = 4 VGPRs

__device__ __forceinline__ float bf2f(unsigned short u) {
    unsigned int x = ((unsigned int)u) << 16;
    return __uint_as_float(x);
}
__device__ __forceinline__ unsigned short f2bf(float f) {
    unsigned int x = __float_as_uint(f);
    unsigned int lsb = (x >> 16) & 1u;
    x += 0x7fffu + lsb;
    return (unsigned short)(x >> 16);
}

__global__ void zero_deg_kernel(int* deg) {
    int i = blockIdx.x * blockDim.x + threadIdx.x;
    if (i < N_NODES) deg[i] = 0;
}

__global__ void count_deg_kernel(const int* __restrict__ dst, int* __restrict__ deg) {
    int e = blockIdx.x * blockDim.x + threadIdx.x;
    if (e < N_EDGES) atomicAdd(&deg[dst[e]], 1);
}

__global__ __launch_bounds__(SCAN_BLK) void scan1_kernel(const int* __restrict__ deg,
                                                         int* __restrict__ local,
                                                         int* __restrict__ bsum) {
    __shared__ int buf[SCAN_BLK];
    int tid = threadIdx.x;
    int i = blockIdx.x * SCAN_BLK + tid;
    int v = (i < N_NODES) ? deg[i] : 0;
    buf[tid] = v;
    __syncthreads();
#pragma unroll
    for (int off = 1; off < SCAN_BLK; off <<= 1) {
        int t = (tid >= off) ? buf[tid - off] : 0;
        __syncthreads();
        buf[tid] += t;
        __syncthreads();
    }
    if (i < N_NODES) local[i] = buf[tid] - v;
    if (tid == SCAN_BLK - 1) bsum[blockIdx.x] = buf[tid];
}

__global__ __launch_bounds__(SCAN_BLK) void scan2_kernel(int* __restrict__ bsum,
                                                         int* __restrict__ row_ptr) {
    __shared__ int buf[SCAN_BLK];
    int tid = threadIdx.x;
    int v = (tid < N_SCAN_BLKS) ? bsum[tid] : 0;
    buf[tid] = v;
    __syncthreads();
#pragma unroll
    for (int off = 1; off < SCAN_BLK; off <<= 1) {
        int t = (tid >= off) ? buf[tid - off] : 0;
        __syncthreads();
        buf[tid] += t;
        __syncthreads();
    }
    if (tid < N_SCAN_BLKS) bsum[tid] = buf[tid] - v;
    if (tid == SCAN_BLK - 1) row_ptr[N_NODES] = buf[tid];
}

__global__ __launch_bounds__(SCAN_BLK) void scan3_kernel(const int* __restrict__ deg,
                                                         const int* __restrict__ local,
                                                         const int* __restrict__ bsum,
                                                         int* __restrict__ row_ptr,
                                                         int* __restrict__ cursor,
                                                         float* __restrict__ inv_deg) {
    int i = blockIdx.x * SCAN_BLK + threadIdx.x;
    if (i < N_NODES) {
        int rp = local[i] + bsum[blockIdx.x];
        row_ptr[i] = rp;
        cursor[i] = rp;
        inv_deg[i] = 1.0f / fmaxf((float)deg[i], 1.0f);
    }
}

// XCD-sliced CSR fill: slice = blockIdx & 7 -> (round-robin dispatch) one XCD per slice.
// Each slice's blocks scan ALL edges, commit only dst in [lo,hi). csr/cursor lines for a
// slice are touched by one XCD only -> written back once (kills the 16x write amplification).
__global__ __launch_bounds__(256) void fill_csr_sliced_kernel(const int* __restrict__ src,
                                                              const int* __restrict__ dst,
                                                              int* __restrict__ cursor,
                                                              int* __restrict__ csr_src) {
    int slice = blockIdx.x & (NSLICE - 1);
    int bid = blockIdx.x >> 3;              // block index within slice
    int lo = slice * SLICE_NODES, hi = lo + SLICE_NODES;
    int stride = FILL_BLKS_PER_SLICE * 256;
    for (int e = bid * 256 + threadIdx.x; e < N_EDGES; e += stride) {
        int d = dst[e];
        if (d >= lo && d < hi) {
            int p = atomicAdd(&cursor[d], 1);
            csr_src[p] = src[e];
        }
    }
}

// Pack GEMM-A weights into MFMA B-fragment order (bf16).
// Bpk[((ct*4+kb)*64+l)*8+j] = W[k][c], k=kb*32+(l>>4)*8+j, c=ct*16+(l&15).
// Logical W[128][256] = [W_self0 | W_neigh0].
__global__ void pack_w0_kernel(const float* __restrict__ Ws, const float* __restrict__ Wn,
                               unsigned short* __restrict__ Bpk) {
    int i = blockIdx.x * blockDim.x + threadIdx.x;
    if (i >= 128 * 256) return;
    int j = i & 7, l = (i >> 3) & 63, kb = (i >> 9) & 3, ct = i >> 11;
    int k = kb * 32 + (l >> 4) * 8 + j;
    int c = ct * 16 + (l & 15);
    float v = (c < F) ? Ws[k * F + c] : Wn[k * F + (c - F)];
    Bpk[i] = f2bf(v);
}

// Pack GEMM-B weights: logical W[128][128], cols 0..40 = W_self1, 64..104 = W_neigh1, else 0.
__global__ void pack_w1_kernel(const float* __restrict__ Ws, const float* __restrict__ Wn,
                               unsigned short* __restrict__ Bpk) {
    int i = blockIdx.x * blockDim.x + threadIdx.x;
    if (i >= 128 * 128) return;
    int j = i & 7, l = (i >> 3) & 63, kb = (i >> 9) & 3, ct = i >> 11;
    int k = kb * 32 + (l >> 4) * 8 + j;
    int c = ct * 16 + (l & 15);
    float v = 0.0f;
    if (c < 48) { if (c < NC) v = Ws[k * NC + c]; }
    else if (c >= 64 && c < 112) { int cc = c - 64; if (cc < NC) v = Wn[k * NC + cc]; }
    Bpk[i] = f2bf(v);
}

// MFMA GEMM: C[M][4*CT*16] = A[M][128] @ W. 64-row tile/block, 4 waves, wave covers CT*16 cols.
// AF32: A is fp32 (converted to bf16 during LDS staging); else A is bf16.
// MODE 0: write all cols bf16 to outA[M][CT*64].
// MODE 1 (CT=2): cols<48 -> outA[M][48], 64<=c<112 -> outB[M][48] (both bf16).
template<bool AF32, int CT, int MODE>
__global__ __launch_bounds__(256) void gemm_mfma_kernel(const void* __restrict__ Av,
                                                        const unsigned short* __restrict__ Bpk,
                                                        int M,
                                                        unsigned short* __restrict__ outA,
                                                        unsigned short* __restrict__ outB) {
    __shared__ unsigned short As[64 * 128];  // bf16, XOR-swizzled: idx ^= (row&7)<<3
    int tid = threadIdx.x;
    int wave = tid >> 6, lane = tid & 63;
    int row0 = blockIdx.x * 64;

    if (AF32) {
        const float* A = (const float*)Av;
#pragma unroll
        for (int i = 0; i < 8; ++i) {
            int fid = tid + i * 256;            // float4 id: 2048 total (64 rows x 32)
            int row = fid >> 5, c4 = (fid & 31) * 4;
            int grow = row0 + row; if (grow > M - 1) grow = M - 1;
            f32x4 v = *(const f32x4*)(A + (size_t)grow * F + c4);
            unsigned int p0 = (unsigned)f2bf(v.x) | ((unsigned)f2bf(v.y) << 16);
            unsigned int p1 = (unsigned)f2bf(v.z) | ((unsigned)f2bf(v.w) << 16);
            int idx = (row * 128 + c4) ^ ((row & 7) << 3);
            *(uint2*)&As[idx] = make_uint2(p0, p1);
        }
    } else {
        const unsigned short* A = (const unsigned short*)Av;
#pragma unroll
        for (int i = 0; i < 4; ++i) {
            int fid = tid + i * 256;            // uint4 id: 1024 total (64 rows x 16 chunks of 8 bf16)
            int row = fid >> 4, c8 = (fid & 15) * 8;
            int grow = row0 + row; if (grow > M - 1) grow = M - 1;
            uint4 v = *(const uint4*)&A[(size_t)grow * F + c8];
            int idx = (row * 128 + c8) ^ ((row & 7) << 3);
            *(uint4*)&As[idx] = v;
        }
    }
    __syncthreads();

    f32x4 acc[4][CT];
#pragma unroll
    for (int m = 0; m < 4; ++m)
#pragma unroll
        for (int n = 0; n < CT; ++n) acc[m][n] = (f32x4){0.f, 0.f, 0.f, 0.f};

#pragma unroll
    for (int kb = 0; kb < 4; ++kb) {
        bf16x8 afr[4];
#pragma unroll
        for (int m = 0; m < 4; ++m) {
            int row = m * 16 + (lane & 15);
            int ke = kb * 32 + (lane >> 4) * 8;
            int idx = (row * 128 + ke) ^ ((row & 7) << 3);
            afr[m] = *(const bf16x8*)&As[idx];
        }
#pragma unroll
        for (int n = 0; n < CT; ++n) {
            int ct = wave * CT + n;
            bf16x8 bfr = *(const bf16x8*)&Bpk[((ct * 4 + kb) * 64 + lane) * 8];
#pragma unroll
            for (int m = 0; m < 4; ++m)
                acc[m][n] = __builtin_amdgcn_mfma_f32_16x16x32_bf16(afr[m], bfr, acc[m][n], 0, 0, 0);
        }
    }

#pragma unroll
    for (int m = 0; m < 4; ++m) {
#pragma unroll
        for (int i = 0; i < 4; ++i) {
            int r = row0 + m * 16 + (lane >> 4) * 4 + i;
            if (r < M) {
#pragma unroll
                for (int n = 0; n < CT; ++n) {
                    int c = (wave * CT + n) * 16 + (lane & 15);
                    unsigned short val = f2bf(acc[m][n][i]);
                    if (MODE == 0) {
                        outA[(size_t)r * (CT * 64) + c] = val;
                    } else {
                        if (c < 48) outA[(size_t)r * 48 + c] = val;
                        else if (c >= 64 && c < 112) outB[(size_t)r * 48 + (c - 64)] = val;
                    }
                }
            }
        }
    }
}

// h[node] = relu(u_self + mean(u_neigh) + b0); u is bf16 [N][256] (self cols 0..127, neigh 128..255).
// One wave/node; lane t handles 2 cols via uint. h written bf16 [N][128].
__global__ __launch_bounds__(64) void agg0_kernel(const unsigned int* __restrict__ u,
                                                  const int* __restrict__ row_ptr,
                                                  const int* __restrict__ csr_src,
                                                  const float* __restrict__ inv_deg,
                                                  const float* __restrict__ b0,
                                                  unsigned int* __restrict__ hu) {
    int node = blockIdx.x;
    int t = threadIdx.x;
    int s = row_ptr[node], e = row_ptr[node + 1];
    float ax = 0.f, ay = 0.f;
    for (int j = s; j < e; ++j) {
        int sr = csr_src[j];
        unsigned int v = u[(size_t)sr * 128 + 64 + t];
        ax += bf2f((unsigned short)(v & 0xffffu));
        ay += bf2f((unsigned short)(v >> 16));
    }
    float inv = inv_deg[node];
    unsigned int vs = u[(size_t)node * 128 + t];
    float2 bb = ((const float2*)b0)[t];
    float h0 = fmaxf(bf2f((unsigned short)(vs & 0xffffu)) + ax * inv + bb.x, 0.0f);
    float h1 = fmaxf(bf2f((unsigned short)(vs >> 16)) + ay * inv + bb.y, 0.0f);
    hu[(size_t)node * 64 + t] = (unsigned)f2bf(h0) | ((unsigned)f2bf(h1) << 16);
}

// out[node][c] = t_self[node][c] + b1[c] + mean(t_neigh[src][c]); t_* bf16 [N][48].
__global__ __launch_bounds__(64) void final_out_kernel(const unsigned int* __restrict__ ts,
                                                       const unsigned int* __restrict__ tn,
                                                       const int* __restrict__ row_ptr,
                                                       const int* __restrict__ csr_src,
                                                       const float* __restrict__ inv_deg,
                                                       const float* __restrict__ b1,
                                                       float* __restrict__ out) {
    int node = blockIdx.x;
    int c = threadIdx.x;  // active 0..23
    if (c >= 24) return;
    int s = row_ptr[node], e = row_ptr[node + 1];
    float ax = 0.f, ay = 0.f;
    for (int j = s; j < e; ++j) {
        int sr = csr_src[j];
        unsigned int v = tn[(size_t)sr * 24 + c];
        ax += bf2f((unsigned short)(v & 0xffffu));
        ay += bf2f((unsigned short)(v >> 16));
    }
    float inv = inv_deg[node];
    unsigned int vs = ts[(size_t)node * 24 + c];
    int c0 = 2 * c, c1 = 2 * c + 1;
    if (c0 < NC)
        out[(size_t)node * NC + c0] = bf2f((unsigned short)(vs & 0xffffu)) + b1[c0] + ax * inv;
    if (c1 < NC)
        out[(size_t)node * NC + c1] = bf2f((unsigned short)(vs >> 16)) + b1[c1] + ay * inv;
}

extern "C" void kernel_launch(void* const* d_in, const int* in_sizes, int n_in,
                              void* d_out, int out_size, void* d_ws, size_t ws_size,
                              hipStream_t stream) {
    const float* x   = (const float*)d_in[0];
    const int*   src = (const int*)d_in[1];
    const int*   dst = (const int*)d_in[2];
    const float* Ws0 = (const float*)d_in[3];
    const float* Wn0 = (const float*)d_in[4];
    const float* b0  = (const float*)d_in[5];
    const float* Ws1 = (const float*)d_in[6];
    const float* Wn1 = (const float*)d_in[7];
    const float* b1  = (const float*)d_in[8];
    float* out = (float*)d_out;

    char* ws = (char*)d_ws;
    size_t o = 0;
    auto alloc = [&](size_t bytes) {
        size_t r = o;
        o = (o + bytes + 255) & ~(size_t)255;
        return r;
    };
    int*   deg     = (int*)(ws + alloc(sizeof(int) * N_NODES));
    int*   local   = (int*)(ws + alloc(sizeof(int) * N_NODES));
    int*   bsum    = (int*)(ws + alloc(sizeof(int) * N_SCAN_BLKS));
    int*   row_ptr = (int*)(ws + alloc(sizeof(int) * (N_NODES + 1)));
    int*   cursor  = (int*)(ws + alloc(sizeof(int) * N_NODES));
    int*   csr     = (int*)(ws + alloc(sizeof(int) * N_EDGES));
    float* inv_deg = (float*)(ws + alloc(sizeof(float) * N_NODES));
    unsigned short* Bpk0 = (unsigned short*)(ws + alloc(sizeof(short) * 128 * 256));
    unsigned short* Bpk1 = (unsigned short*)(ws + alloc(sizeof(short) * 128 * 128));
    unsigned short* u    = (unsigned short*)(ws + alloc(sizeof(short) * (size_t)N_NODES * 256));
    unsigned short* h    = (unsigned short*)(ws + alloc(sizeof(short) * (size_t)N_NODES * 128));
    unsigned short* t_self  = (unsigned short*)(ws + alloc(sizeof(short) * (size_t)N_NODES * 48));
    unsigned short* t_neigh = (unsigned short*)(ws + alloc(sizeof(short) * (size_t)N_NODES * 48));

    zero_deg_kernel<<<(N_NODES + 255) / 256, 256, 0, stream>>>(deg);
    count_deg_kernel<<<(N_EDGES + 255) / 256, 256, 0, stream>>>(dst, deg);
    scan1_kernel<<<N_SCAN_BLKS, SCAN_BLK, 0, stream>>>(deg, local, bsum);
    scan2_kernel<<<1, SCAN_BLK, 0, stream>>>(bsum, row_ptr);
    scan3_kernel<<<N_SCAN_BLKS, SCAN_BLK, 0, stream>>>(deg, local, bsum, row_ptr, cursor, inv_deg);
    fill_csr_sliced_kernel<<<NSLICE * FILL_BLKS_PER_SLICE, 256, 0, stream>>>(src, dst, cursor, csr);
    pack_w0_kernel<<<(128 * 256 + 255) / 256, 256, 0, stream>>>(Ws0, Wn0, Bpk0);
    pack_w1_kernel<<<(128 * 128 + 255) / 256, 256, 0, stream>>>(Ws1, Wn1, Bpk1);

    int nblk = (N_NODES + 63) / 64;  // 782
    // GEMM A: u = bf16(x) @ [Ws0|Wn0]  -> u bf16 [N][256]
    gemm_mfma_kernel<true, 4, 0><<<nblk, 256, 0, stream>>>(x, Bpk0, N_NODES, u, nullptr);
    // agg0: h = relu(u_self + mean(u_neigh) + b0) -> bf16 [N][128]
    agg0_kernel<<<N_NODES, 64, 0, stream>>>((const unsigned int*)u, row_ptr, csr, inv_deg, b0,
                                            (unsigned int*)h);
    // GEMM B: t = h @ Wcat1 -> t_self bf16[N][48], t_neigh bf16[N][48]
    gemm_mfma_kernel<false, 2, 1><<<nblk, 256, 0, stream>>>(h, Bpk1, N_NODES, t_self, t_neigh);
    // final: out = t_self + b1 + mean(t_neigh)
    final_out_kernel<<<N_NODES, 64, 0, stream>>>((const unsigned int*)t_self,
                                                 (const unsigned int*)t_neigh,
                                                 row_ptr, csr, inv_deg, b1, out);
}